// Round 6
// baseline (544.729 us; speedup 1.0000x reference)
//
#include <hip/hip_runtime.h>
#include <math.h>

// ---------------------------------------------------------------------------
// SPA graph conv, 2 layers. N=50000, E=800000, C=128, OUT=64, HS=16, K=4.
// R6: half-wave node parallelism in the two gather kernels: each 32-lane
//     half owns a node, lane owns 4 channels (uint2 of bf16 pairs). One load
//     instruction covers 2 edges (512B); 2 independent chains/wave double
//     memory-level parallelism. Softmax reductions are width-32 shuffles.
// ---------------------------------------------------------------------------

__device__ __forceinline__ float wave_sum(float v) {
#pragma unroll
  for (int o = 32; o; o >>= 1) v += __shfl_xor(v, o, 64);
  return v;
}
__device__ __forceinline__ float half_max(float v) {
#pragma unroll
  for (int o = 16; o; o >>= 1) v = fmaxf(v, __shfl_xor(v, o, 32));
  return v;
}
__device__ __forceinline__ float half_sum(float v) {
#pragma unroll
  for (int o = 16; o; o >>= 1) v += __shfl_xor(v, o, 32);
  return v;
}

// bf16 pair packed in a uint: low ushort = even channel, high = odd channel.
__device__ __forceinline__ float bflo(unsigned u) {
  return __uint_as_float(u << 16);
}
__device__ __forceinline__ float bfhi(unsigned u) {
  return __uint_as_float(u & 0xffff0000u);
}
__device__ __forceinline__ unsigned f2bf(float f) {  // RNE
  unsigned x = __float_as_uint(f);
  return (x + 0x7fffu + ((x >> 16) & 1u)) >> 16;
}
__device__ __forceinline__ unsigned packbf(float a, float b) {
  return f2bf(a) | (f2bf(b) << 16);
}

// ---------------------------------------------------------------------------
// GEMM: Y[r][c] = sum_k X[r][k]*W[c][k] + bias[c].  K fixed = 128.
// BFOUT additionally writes a bf16 shadow copy (row-major, uint = ch pair).
// ---------------------------------------------------------------------------
template <int COLS, bool BFOUT>
__global__ __launch_bounds__(256) void gemm_bias(
    const float* __restrict__ X, const float* __restrict__ W,
    const float* __restrict__ bias, float* __restrict__ Y,
    unsigned* __restrict__ Yb, int nrows) {
  __shared__ float Wt[128 * COLS];
  const int t = threadIdx.x;
  for (int q = t; q < COLS * 32; q += 256) {
    const int c = q >> 5;
    const int k0 = (q & 31) << 2;
    const float4 w = *(const float4*)(W + c * 128 + k0);
    Wt[(k0 + 0) * COLS + c] = w.x;
    Wt[(k0 + 1) * COLS + c] = w.y;
    Wt[(k0 + 2) * COLS + c] = w.z;
    Wt[(k0 + 3) * COLS + c] = w.w;
  }
  __syncthreads();
  const int tx = t & 15, ty = t >> 4;
  const long rbase = (long)blockIdx.x * 128 + ty * 8;
  constexpr int NG = COLS / 64;
  float acc[8][NG * 4];
#pragma unroll
  for (int i = 0; i < 8; i++)
#pragma unroll
    for (int j = 0; j < NG * 4; j++) acc[i][j] = 0.0f;
  const float* xp[8];
#pragma unroll
  for (int i = 0; i < 8; i++) {
    long r = rbase + i;
    if (r > nrows - 1) r = nrows - 1;
    xp[i] = X + r * 128;
  }
  for (int k0 = 0; k0 < 128; k0 += 4) {
    float4 xv[8];
#pragma unroll
    for (int i = 0; i < 8; i++) xv[i] = *(const float4*)(xp[i] + k0);
#pragma unroll
    for (int kk = 0; kk < 4; kk++) {
      float4 wv[NG];
#pragma unroll
      for (int g = 0; g < NG; g++)
        wv[g] = *(const float4*)(&Wt[(k0 + kk) * COLS + g * 64 + 4 * tx]);
#pragma unroll
      for (int i = 0; i < 8; i++) {
        const float xs = ((const float*)&xv[i])[kk];
#pragma unroll
        for (int g = 0; g < NG; g++) {
          acc[i][g * 4 + 0] = fmaf(xs, wv[g].x, acc[i][g * 4 + 0]);
          acc[i][g * 4 + 1] = fmaf(xs, wv[g].y, acc[i][g * 4 + 1]);
          acc[i][g * 4 + 2] = fmaf(xs, wv[g].z, acc[i][g * 4 + 2]);
          acc[i][g * 4 + 3] = fmaf(xs, wv[g].w, acc[i][g * 4 + 3]);
        }
      }
    }
  }
  float4 bv[NG];
#pragma unroll
  for (int g = 0; g < NG; g++) bv[g] = *(const float4*)(bias + g * 64 + 4 * tx);
#pragma unroll
  for (int i = 0; i < 8; i++) {
    const long r = rbase + i;
    if (r < nrows) {
#pragma unroll
      for (int g = 0; g < NG; g++) {
        float4 o;
        o.x = acc[i][g * 4 + 0] + bv[g].x;
        o.y = acc[i][g * 4 + 1] + bv[g].y;
        o.z = acc[i][g * 4 + 2] + bv[g].z;
        o.w = acc[i][g * 4 + 3] + bv[g].w;
        const int c = g * 64 + 4 * tx;
        *(float4*)(Y + r * COLS + c) = o;
        if (BFOUT) {
          uint2 p;
          p.x = packbf(o.x, o.y);
          p.y = packbf(o.z, o.w);
          *(uint2*)(Yb + r * (COLS / 2) + (c >> 1)) = p;
        }
      }
    }
  }
}

// ---------------------------------------------------------------------------
// Edge moment stats, half-wave per node, bf16 gather (uint2 = 4 channels).
// stat[0:128] = sum_e (x_s-x_d)^2, stat[128:256] = sum of squares of that.
// Self-loop entries contribute exactly 0; denominator Ef=E downstream.
// ---------------------------------------------------------------------------
__global__ __launch_bounds__(256) void edge_stats_bf(
    const unsigned* __restrict__ Xb, const int* __restrict__ csr,
    const int* __restrict__ offs, int n, float* __restrict__ stat) {
  __shared__ float pS[128];
  __shared__ float pQ[128];
  const uint2* __restrict__ Xb2 = (const uint2*)Xb;
  const int t = threadIdx.x;
  const int q = t & 31;  // lane in half; owns channels 4q..4q+3
  const int hw = blockIdx.x * 8 + (t >> 5);
  const int nhw = gridDim.x * 8;
  float ss[4] = {0.f, 0.f, 0.f, 0.f};
  float qq[4] = {0.f, 0.f, 0.f, 0.f};
  for (int i = hw; i < n; i += nhw) {
    const int beg = offs[i], end = offs[i + 1];
    const int deg = end - beg;
    const uint2 ud = Xb2[(long)i * 32 + q];
    const float xd[4] = {bflo(ud.x), bfhi(ud.x), bflo(ud.y), bfhi(ud.y)};
    if (deg <= 128) {
      int s[4];
#pragma unroll
      for (int m = 0; m < 4; ++m) {
        const int p = (m << 5) + q;
        s[m] = (p < deg) ? csr[beg + p] : 0;
      }
#pragma unroll 4
      for (int m = 0; m < 4; ++m) {
        const int kbase = m << 5;
        if (kbase >= deg) break;
        const int sm = s[m];
        const int lim = min(32, deg - kbase);
        int k = 0;
        for (; k + 4 <= lim; k += 4) {
          int sx[4];
          uint2 ua[4];
#pragma unroll
          for (int j = 0; j < 4; j++) sx[j] = __shfl(sm, k + j, 32);
#pragma unroll
          for (int j = 0; j < 4; j++) ua[j] = Xb2[(long)sx[j] * 32 + q];
#pragma unroll
          for (int j = 0; j < 4; j++) {
            const float xa[4] = {bflo(ua[j].x), bfhi(ua[j].x), bflo(ua[j].y),
                                 bfhi(ua[j].y)};
#pragma unroll
            for (int c = 0; c < 4; c++) {
              float d = xa[c] - xd[c];
              d *= d;
              ss[c] += d;
              qq[c] += d * d;
            }
          }
        }
        for (; k < lim; ++k) {
          const int sx = __shfl(sm, k, 32);
          const uint2 ua = Xb2[(long)sx * 32 + q];
          const float xa[4] = {bflo(ua.x), bfhi(ua.x), bflo(ua.y), bfhi(ua.y)};
#pragma unroll
          for (int c = 0; c < 4; c++) {
            float d = xa[c] - xd[c];
            d *= d;
            ss[c] += d;
            qq[c] += d * d;
          }
        }
      }
    } else {
      for (int p = beg; p < end; ++p) {
        const int sx = csr[p];
        const uint2 ua = Xb2[(long)sx * 32 + q];
        const float xa[4] = {bflo(ua.x), bfhi(ua.x), bflo(ua.y), bfhi(ua.y)};
#pragma unroll
        for (int c = 0; c < 4; c++) {
          float d = xa[c] - xd[c];
          d *= d;
          ss[c] += d;
          qq[c] += d * d;
        }
      }
    }
  }
  if (t < 128) {
    pS[t] = 0.0f;
    pQ[t] = 0.0f;
  }
  __syncthreads();
#pragma unroll
  for (int c = 0; c < 4; c++) {
    atomicAdd(&pS[4 * q + c], ss[c]);
    atomicAdd(&pQ[4 * q + c], qq[c]);
  }
  __syncthreads();
  if (t < 128) {
    atomicAdd(&stat[t], pS[t]);
    atomicAdd(&stat[128 + t], pQ[t]);
  }
}

// ---------------------------------------------------------------------------
// Attention vectors from stats. One block of 128 threads (thread = channel).
// ---------------------------------------------------------------------------
__global__ __launch_bounds__(128) void compute_att(
    const float* __restrict__ stat, const float* __restrict__ src_w,
    const float* __restrict__ src_b, const float* __restrict__ dst_w,
    const float* __restrict__ dst_b, const float* __restrict__ tq,
    float* __restrict__ att_l, float* __restrict__ att_r, float Ef) {
  const int c = threadIdx.x;
  __shared__ float red[4][128];
  const float sum = stat[c], sq = stat[128 + c];
  const float m1 = sum / Ef;
  float var = (sq - sum * (sum / Ef)) / (Ef - 1.0f);
  var = fmaxf(var, 0.0f);
  const float sd = sqrtf(var);
  const float m2 = sd + 1e-5f;
  float S[4];
  S[0] = m1;
  S[1] = sd;
  S[2] = (m1 * m1 * m1) / (m2 * m2 * m2);
  const float m12 = m1 * m1, m22 = m2 * m2;
  S[3] = (m12 * m12) / (m22 * m22);
#pragma unroll
  for (int j = 0; j < 4; j++) {
    if (isnan(S[j])) S[j] = 0.0f;
    S[j] = tanhf(S[j]);
    red[j][c] = S[j] * S[j];
  }
  for (int o = 64; o; o >>= 1) {
    __syncthreads();
    if (c < o) {
#pragma unroll
      for (int j = 0; j < 4; j++) red[j][c] += red[j][c + o];
    }
  }
  __syncthreads();
#pragma unroll
  for (int j = 0; j < 4; j++) S[j] /= fmaxf(sqrtf(red[j][0]), 1e-12f);
  float al = 0.0f, ar = 0.0f;
#pragma unroll
  for (int j = 0; j < 16; j++) {
    float tl = src_b[j], tr = dst_b[j];
#pragma unroll
    for (int k = 0; k < 4; k++) {
      tl += S[k] * src_w[j * 4 + k];
      tr += S[k] * dst_w[j * 4 + k];
    }
    al += tq[j] * tl;
    ar += tq[j] * tr;
  }
  att_l[c] = al;
  att_r[c] = ar;
}

// ---------------------------------------------------------------------------
// Per-node scores (fp32 stream): a_src=dot(X,att_l), a_dst=dot(X,att_r).
// ---------------------------------------------------------------------------
__global__ __launch_bounds__(256) void node_scores(
    const float* __restrict__ X, const float* __restrict__ attl,
    const float* __restrict__ attr, float* __restrict__ a_src,
    float* __restrict__ a_dst, int n) {
  const int t = threadIdx.x, l = t & 63;
  const float2 al = ((const float2*)attl)[l];
  const float2 ar = ((const float2*)attr)[l];
  const int wid = blockIdx.x * 4 + (t >> 6);
  const int nw = gridDim.x * 4;
  for (int i = wid; i < n; i += nw) {
    const float2 xv = ((const float2*)(X + (long)i * 128))[l];
    float sl = xv.x * al.x + xv.y * al.y;
    float sr = xv.x * ar.x + xv.y * ar.y;
    sl = wave_sum(sl);
    sr = wave_sum(sr);
    if (l == 0) {
      a_src[i] = sl;
      a_dst[i] = sr;
    }
  }
}

// ---------------------------------------------------------------------------
// CSR build (by dst, self-loops included via deg init = 1)
// ---------------------------------------------------------------------------
__global__ void init_deg(int* deg, int n) {
  int i = blockIdx.x * 256 + threadIdx.x;
  if (i < n) deg[i] = 1;
}
__global__ void hist_dst(const int* __restrict__ edst, int E, int* deg) {
  int e = blockIdx.x * 256 + threadIdx.x;
  if (e < E) atomicAdd(&deg[edst[e]], 1);
}
__global__ __launch_bounds__(256) void scan_partial(const int* __restrict__ deg,
                                                    int n, int* bsum) {
  __shared__ int r[256];
  int t = threadIdx.x;
  int g = blockIdx.x * 256 + t;
  r[t] = (g < n) ? deg[g] : 0;
  for (int o = 128; o; o >>= 1) {
    __syncthreads();
    if (t < o) r[t] += r[t + o];
  }
  if (t == 0) bsum[blockIdx.x] = r[0];
}
__global__ __launch_bounds__(256) void scan_bsums(int* bsum, int nb) {
  __shared__ int r[256];
  int t = threadIdx.x;
  int v = (t < nb) ? bsum[t] : 0;
  r[t] = v;
  for (int o = 1; o < 256; o <<= 1) {
    int x = 0;
    __syncthreads();
    if (t >= o) x = r[t - o];
    __syncthreads();
    r[t] += x;
  }
  if (t < nb) bsum[t] = r[t] - v;  // exclusive
}
__global__ __launch_bounds__(256) void scan_final(const int* __restrict__ deg,
                                                  int n,
                                                  const int* __restrict__ bsum,
                                                  int* offs, int* cursor) {
  __shared__ int r[256];
  int t = threadIdx.x;
  int g = blockIdx.x * 256 + t;
  int v = (g < n) ? deg[g] : 0;
  r[t] = v;
  for (int o = 1; o < 256; o <<= 1) {
    int x = 0;
    __syncthreads();
    if (t >= o) x = r[t - o];
    __syncthreads();
    r[t] += x;
  }
  int excl = bsum[blockIdx.x] + r[t] - v;
  if (g < n) {
    offs[g] = excl;
    cursor[g] = excl;
    if (g == n - 1) offs[n] = excl + v;
  }
}
__global__ void scatter_csr(const int* __restrict__ esrc,
                            const int* __restrict__ edst, int E, int n,
                            int* cursor, int* __restrict__ csr) {
  int g = blockIdx.x * 256 + threadIdx.x;
  if (g < E) {
    int d = edst[g];
    int p = atomicAdd(&cursor[d], 1);
    csr[p] = esrc[g];
  } else if (g < E + n) {
    int i = g - E;
    int p = atomicAdd(&cursor[i], 1);
    csr[p] = i;
  }
}

// ---------------------------------------------------------------------------
// Softmax aggregation, half-wave per node, bf16 gather (uint2 = 4 channels).
// Setup: up to 4 csr/a_src slots per lane, width-32 softmax reduction, then
// blocked accumulate with (src,alpha) broadcast from registers.
// ---------------------------------------------------------------------------
__global__ __launch_bounds__(256) void aggregate_bf(
    const unsigned* __restrict__ Xb, const int* __restrict__ csr,
    const int* __restrict__ offs, const float* __restrict__ a_src,
    const float* __restrict__ a_dst, const float* __restrict__ bias,
    float* __restrict__ Y, unsigned* __restrict__ Yb, int n, int do_relu,
    int write_bf) {
  const uint2* __restrict__ Xb2 = (const uint2*)Xb;
  const int t = threadIdx.x;
  const int q = t & 31;  // lane in half; owns channels 4q..4q+3
  const int hw = blockIdx.x * 8 + (t >> 5);
  const int nhw = gridDim.x * 8;
  const float4 b4 = ((const float4*)bias)[q];
  for (int i = hw; i < n; i += nhw) {
    const int beg = offs[i], end = offs[i + 1];
    const int deg = end - beg;
    const float adsti = a_dst[i];
    float acc[4] = {0.f, 0.f, 0.f, 0.f};
    if (deg <= 128) {
      int s[4];
      float a[4];
#pragma unroll
      for (int m = 0; m < 4; ++m) {
        const int p = (m << 5) + q;
        if (p < deg) {
          s[m] = csr[beg + p];
          float v = a_src[s[m]] + adsti;
          a[m] = (v > 0.0f ? v : 0.2f * v) * 0.1f;
        } else {
          s[m] = 0;
          a[m] = -INFINITY;
        }
      }
      const float mx =
          half_max(fmaxf(fmaxf(a[0], a[1]), fmaxf(a[2], a[3])));
      float al[4];
      float esum = 0.0f;
#pragma unroll
      for (int m = 0; m < 4; ++m) {
        al[m] = expf(a[m] - mx);  // exp(-inf)=0 for idle slots
        esum += al[m];
      }
      const float inv = 1.0f / (half_sum(esum) + 1e-16f);
#pragma unroll
      for (int m = 0; m < 4; ++m) al[m] *= inv;
#pragma unroll 4
      for (int m = 0; m < 4; ++m) {
        const int kbase = m << 5;
        if (kbase >= deg) break;
        const int sm = s[m];
        const float am = al[m];
        const int lim = min(32, deg - kbase);
        int k = 0;
        for (; k + 4 <= lim; k += 4) {
          int sx[4];
          float w[4];
          uint2 ua[4];
#pragma unroll
          for (int j = 0; j < 4; j++) {
            sx[j] = __shfl(sm, k + j, 32);
            w[j] = __shfl(am, k + j, 32);
          }
#pragma unroll
          for (int j = 0; j < 4; j++) ua[j] = Xb2[(long)sx[j] * 32 + q];
#pragma unroll
          for (int j = 0; j < 4; j++) {
            acc[0] = fmaf(w[j], bflo(ua[j].x), acc[0]);
            acc[1] = fmaf(w[j], bfhi(ua[j].x), acc[1]);
            acc[2] = fmaf(w[j], bflo(ua[j].y), acc[2]);
            acc[3] = fmaf(w[j], bfhi(ua[j].y), acc[3]);
          }
        }
        for (; k < lim; ++k) {
          const int sx = __shfl(sm, k, 32);
          const float w = __shfl(am, k, 32);
          const uint2 ua = Xb2[(long)sx * 32 + q];
          acc[0] = fmaf(w, bflo(ua.x), acc[0]);
          acc[1] = fmaf(w, bfhi(ua.x), acc[1]);
          acc[2] = fmaf(w, bflo(ua.y), acc[2]);
          acc[3] = fmaf(w, bfhi(ua.y), acc[3]);
        }
      }
    } else {
      // 3-pass fallback (deg > 128), 32-lane
      float mx = -1e30f;
      for (int p = beg + q; p < end; p += 32) {
        float v = a_src[csr[p]] + adsti;
        v = (v > 0.0f ? v : 0.2f * v) * 0.1f;
        mx = fmaxf(mx, v);
      }
      mx = half_max(mx);
      float sm = 0.0f;
      for (int p = beg + q; p < end; p += 32) {
        float v = a_src[csr[p]] + adsti;
        v = (v > 0.0f ? v : 0.2f * v) * 0.1f;
        sm += expf(v - mx);
      }
      sm = half_sum(sm);
      const float inv = 1.0f / (sm + 1e-16f);
      for (int p = beg; p < end; ++p) {
        const int sx = csr[p];
        float v = a_src[sx] + adsti;
        v = (v > 0.0f ? v : 0.2f * v) * 0.1f;
        const float w = expf(v - mx) * inv;
        const uint2 ua = Xb2[(long)sx * 32 + q];
        acc[0] = fmaf(w, bflo(ua.x), acc[0]);
        acc[1] = fmaf(w, bfhi(ua.x), acc[1]);
        acc[2] = fmaf(w, bflo(ua.y), acc[2]);
        acc[3] = fmaf(w, bfhi(ua.y), acc[3]);
      }
    }
    float4 o;
    o.x = acc[0] + b4.x;
    o.y = acc[1] + b4.y;
    o.z = acc[2] + b4.z;
    o.w = acc[3] + b4.w;
    if (do_relu) {
      o.x = fmaxf(o.x, 0.0f);
      o.y = fmaxf(o.y, 0.0f);
      o.z = fmaxf(o.z, 0.0f);
      o.w = fmaxf(o.w, 0.0f);
    }
    *(float4*)(Y + (long)i * 128 + 4 * q) = o;
    if (write_bf) {
      uint2 p;
      p.x = packbf(o.x, o.y);
      p.y = packbf(o.z, o.w);
      *(uint2*)((unsigned*)Yb + (long)i * 64 + 2 * q) = p;
    }
  }
}

// ---------------------------------------------------------------------------
extern "C" void kernel_launch(void* const* d_in, const int* in_sizes, int n_in,
                              void* d_out, int out_size, void* d_ws,
                              size_t ws_size, hipStream_t stream) {
  (void)n_in;
  (void)out_size;
  (void)ws_size;
  const float* x = (const float*)d_in[0];
  const int* ei = (const int*)d_in[1];
  const float* W0 = (const float*)d_in[2];
  const float* b0 = (const float*)d_in[3];
  const float* W2 = (const float*)d_in[4];
  const float* b2 = (const float*)d_in[5];
  const float* gsw[2] = {(const float*)d_in[6], (const float*)d_in[12]};
  const float* gsb[2] = {(const float*)d_in[7], (const float*)d_in[13]};
  const float* gdw[2] = {(const float*)d_in[8], (const float*)d_in[14]};
  const float* gdb[2] = {(const float*)d_in[9], (const float*)d_in[15]};
  const float* gtq[2] = {(const float*)d_in[10], (const float*)d_in[16]};
  const float* gbias[2] = {(const float*)d_in[11], (const float*)d_in[17]};

  const int N = in_sizes[0] / 128;
  const int E = in_sizes[1] / 2;
  const int* esrc = ei;
  const int* edst = ei + E;

  float* ws = (float*)d_ws;
  size_t o = 0;
  float* h0 = ws + o;
  o += (size_t)N * 128;
  float* h1 = ws + o;
  o += (size_t)N * 128;
  unsigned* h0b = (unsigned*)(ws + o);
  o += (size_t)N * 64;
  unsigned* h1b = (unsigned*)(ws + o);
  o += (size_t)N * 64;
  float* stat = ws + o;
  o += 256;
  float* attl = ws + o;
  o += 128;
  float* attr = ws + o;
  o += 128;
  float* a_src = ws + o;
  o += N;
  float* a_dst = ws + o;
  o += N;
  int* ip = (int*)(ws + o);
  int* deg = ip;
  ip += N;
  int* offs = ip;
  ip += N + 1;
  int* cursor = ip;
  ip += N;
  int* bsum = ip;
  ip += 256;
  int* csr = ip;
  ip += E + N;

  const int NB = (N + 255) / 256;  // 196 <= 256 required by scan_bsums

  // GEMM1: h0 = x @ W0^T + b0  (+ bf16 shadow h0b)
  gemm_bias<128, true><<<(N + 127) / 128, 256, 0, stream>>>(x, W0, b0, h0,
                                                            h0b, N);

  // CSR build (shared by both convs)
  init_deg<<<NB, 256, 0, stream>>>(deg, N);
  hist_dst<<<(E + 255) / 256, 256, 0, stream>>>(edst, E, deg);
  scan_partial<<<NB, 256, 0, stream>>>(deg, N, bsum);
  scan_bsums<<<1, 256, 0, stream>>>(bsum, NB);
  scan_final<<<NB, 256, 0, stream>>>(deg, N, bsum, offs, cursor);
  scatter_csr<<<(E + N + 255) / 256, 256, 0, stream>>>(esrc, edst, E, N,
                                                       cursor, csr);

  for (int layer = 0; layer < 2; ++layer) {
    const float* Xf = layer ? h1 : h0;
    const unsigned* Xb = layer ? h1b : h0b;
    float* Yf = layer ? h0 : h1;
    unsigned* Yb = layer ? h0b : h1b;  // only written for layer 0
    hipMemsetAsync(stat, 0, 256 * sizeof(float), stream);
    edge_stats_bf<<<2048, 256, 0, stream>>>(Xb, csr, offs, N, stat);
    compute_att<<<1, 128, 0, stream>>>(stat, gsw[layer], gsb[layer],
                                       gdw[layer], gdb[layer], gtq[layer],
                                       attl, attr, (float)E);
    node_scores<<<1024, 256, 0, stream>>>(Xf, attl, attr, a_src, a_dst, N);
    aggregate_bf<<<2048, 256, 0, stream>>>(Xb, csr, offs, a_src, a_dst,
                                           gbias[layer], Yf, Yb, N,
                                           layer == 0 ? 1 : 0,
                                           layer == 0 ? 1 : 0);
  }

  // GEMM2: out = h0 @ W2^T + b2   (h0 holds conv2 output, fp32)
  gemm_bias<64, false><<<(N + 127) / 128, 256, 0, stream>>>(
      h0, W2, b2, (float*)d_out, nullptr, N);
}

// Round 7
// 542.873 us; speedup vs baseline: 1.0034x; 1.0034x over previous
//
#include <hip/hip_runtime.h>
#include <math.h>

// ---------------------------------------------------------------------------
// SPA graph conv, 2 layers. N=50000, E=800000, C=128, OUT=64, HS=16, K=4.
// R7: back to R5 gather structure (best so far) +
//   (a) unroll-8 gather loops (8 indep 256B loads in flight per wave),
//   (b) edge-balanced wave->node ranges via binary search on offs
//       (node owned by wave containing its beg edge; kills Poisson tail),
//   (c) compute_att fused into node_scores (each block recomputes from stat),
//   (d) stat zeroed inside init_deg (L0) and aggregate_bf L0 (for L1):
//       no hipMemsetAsync dispatches. 18 -> 14 dispatches.
// ---------------------------------------------------------------------------

__device__ __forceinline__ float wave_max(float v) {
#pragma unroll
  for (int o = 32; o; o >>= 1) v = fmaxf(v, __shfl_xor(v, o, 64));
  return v;
}
__device__ __forceinline__ float wave_sum(float v) {
#pragma unroll
  for (int o = 32; o; o >>= 1) v += __shfl_xor(v, o, 64);
  return v;
}

// bf16 pair packed in a uint: low ushort = even channel, high = odd channel.
__device__ __forceinline__ float bflo(unsigned u) {
  return __uint_as_float(u << 16);
}
__device__ __forceinline__ float bfhi(unsigned u) {
  return __uint_as_float(u & 0xffff0000u);
}
__device__ __forceinline__ unsigned f2bf(float f) {  // RNE
  unsigned x = __float_as_uint(f);
  return (x + 0x7fffu + ((x >> 16) & 1u)) >> 16;
}
__device__ __forceinline__ unsigned packbf(float a, float b) {
  return f2bf(a) | (f2bf(b) << 16);
}

// smallest i in [0,n] with offs[i] >= key
__device__ __forceinline__ int lb_offs(const int* __restrict__ offs, int n,
                                       int key) {
  int lo = 0, hi = n;
  while (lo < hi) {
    const int mid = (lo + hi) >> 1;
    if (offs[mid] < key)
      lo = mid + 1;
    else
      hi = mid;
  }
  return lo;
}

// ---------------------------------------------------------------------------
// GEMM: Y[r][c] = sum_k X[r][k]*W[c][k] + bias[c].  K fixed = 128.
// BFOUT additionally writes a bf16 shadow copy (row-major, uint = ch pair).
// ---------------------------------------------------------------------------
template <int COLS, bool BFOUT>
__global__ __launch_bounds__(256) void gemm_bias(
    const float* __restrict__ X, const float* __restrict__ W,
    const float* __restrict__ bias, float* __restrict__ Y,
    unsigned* __restrict__ Yb, int nrows) {
  __shared__ float Wt[128 * COLS];
  const int t = threadIdx.x;
  for (int q = t; q < COLS * 32; q += 256) {
    const int c = q >> 5;
    const int k0 = (q & 31) << 2;
    const float4 w = *(const float4*)(W + c * 128 + k0);
    Wt[(k0 + 0) * COLS + c] = w.x;
    Wt[(k0 + 1) * COLS + c] = w.y;
    Wt[(k0 + 2) * COLS + c] = w.z;
    Wt[(k0 + 3) * COLS + c] = w.w;
  }
  __syncthreads();
  const int tx = t & 15, ty = t >> 4;
  const long rbase = (long)blockIdx.x * 128 + ty * 8;
  constexpr int NG = COLS / 64;
  float acc[8][NG * 4];
#pragma unroll
  for (int i = 0; i < 8; i++)
#pragma unroll
    for (int j = 0; j < NG * 4; j++) acc[i][j] = 0.0f;
  const float* xp[8];
#pragma unroll
  for (int i = 0; i < 8; i++) {
    long r = rbase + i;
    if (r > nrows - 1) r = nrows - 1;
    xp[i] = X + r * 128;
  }
  for (int k0 = 0; k0 < 128; k0 += 4) {
    float4 xv[8];
#pragma unroll
    for (int i = 0; i < 8; i++) xv[i] = *(const float4*)(xp[i] + k0);
#pragma unroll
    for (int kk = 0; kk < 4; kk++) {
      float4 wv[NG];
#pragma unroll
      for (int g = 0; g < NG; g++)
        wv[g] = *(const float4*)(&Wt[(k0 + kk) * COLS + g * 64 + 4 * tx]);
#pragma unroll
      for (int i = 0; i < 8; i++) {
        const float xs = ((const float*)&xv[i])[kk];
#pragma unroll
        for (int g = 0; g < NG; g++) {
          acc[i][g * 4 + 0] = fmaf(xs, wv[g].x, acc[i][g * 4 + 0]);
          acc[i][g * 4 + 1] = fmaf(xs, wv[g].y, acc[i][g * 4 + 1]);
          acc[i][g * 4 + 2] = fmaf(xs, wv[g].z, acc[i][g * 4 + 2]);
          acc[i][g * 4 + 3] = fmaf(xs, wv[g].w, acc[i][g * 4 + 3]);
        }
      }
    }
  }
  float4 bv[NG];
#pragma unroll
  for (int g = 0; g < NG; g++) bv[g] = *(const float4*)(bias + g * 64 + 4 * tx);
#pragma unroll
  for (int i = 0; i < 8; i++) {
    const long r = rbase + i;
    if (r < nrows) {
#pragma unroll
      for (int g = 0; g < NG; g++) {
        float4 o;
        o.x = acc[i][g * 4 + 0] + bv[g].x;
        o.y = acc[i][g * 4 + 1] + bv[g].y;
        o.z = acc[i][g * 4 + 2] + bv[g].z;
        o.w = acc[i][g * 4 + 3] + bv[g].w;
        const int c = g * 64 + 4 * tx;
        *(float4*)(Y + r * COLS + c) = o;
        if (BFOUT) {
          uint2 p;
          p.x = packbf(o.x, o.y);
          p.y = packbf(o.z, o.w);
          *(uint2*)(Yb + r * (COLS / 2) + (c >> 1)) = p;
        }
      }
    }
  }
}

// ---------------------------------------------------------------------------
// Edge moment stats via CSR, bf16 gather, unroll-8, edge-balanced ranges.
// Wave owns nodes whose beg-edge falls in [wave*T, wave*T+T).
// ---------------------------------------------------------------------------
__global__ __launch_bounds__(256) void edge_stats_bf(
    const unsigned* __restrict__ Xb, const int* __restrict__ csr,
    const int* __restrict__ offs, int n, int T, float* __restrict__ stat) {
  __shared__ float pS[4][128];
  __shared__ float pQ[4][128];
  const int t = threadIdx.x;
  const int w = t >> 6, l = t & 63;
  const int wave = blockIdx.x * 4 + w;
  const int key0 = wave * T;
  const int key1 = key0 + T;
  float s0 = 0.f, q0 = 0.f, s1 = 0.f, q1 = 0.f;
  for (int i = lb_offs(offs, n, key0); i < n; ++i) {
    const int beg = offs[i];
    if (beg >= key1) break;
    const int end = offs[i + 1];
    const int deg = end - beg;
    const unsigned ud = Xb[(long)i * 64 + l];
    const float xd0 = bflo(ud), xd1 = bfhi(ud);
    if (deg <= 128) {
      int s0r = 0, s1r = 0;
      if (l < deg) s0r = csr[beg + l];
      if (64 + l < deg) s1r = csr[beg + 64 + l];
      int k = 0;
      for (; k + 8 <= deg; k += 8) {
        int sx[8];
#pragma unroll
        for (int j = 0; j < 8; j++) {
          const int kk = k + j;
          sx[j] = __shfl(kk < 64 ? s0r : s1r, kk & 63);
        }
        unsigned ua[8];
#pragma unroll
        for (int j = 0; j < 8; j++) ua[j] = Xb[(long)sx[j] * 64 + l];
#pragma unroll
        for (int j = 0; j < 8; j++) {
          float d0 = bflo(ua[j]) - xd0;
          d0 *= d0;
          float d1 = bfhi(ua[j]) - xd1;
          d1 *= d1;
          s0 += d0;
          q0 += d0 * d0;
          s1 += d1;
          q1 += d1 * d1;
        }
      }
      for (; k < deg; ++k) {
        const int s = __shfl(k < 64 ? s0r : s1r, k & 63);
        const unsigned ua = Xb[(long)s * 64 + l];
        float d0 = bflo(ua) - xd0;
        d0 *= d0;
        float d1 = bfhi(ua) - xd1;
        d1 *= d1;
        s0 += d0;
        q0 += d0 * d0;
        s1 += d1;
        q1 += d1 * d1;
      }
    } else {
      for (int p = beg; p < end; ++p) {
        const int s = csr[p];
        const unsigned ua = Xb[(long)s * 64 + l];
        float d0 = bflo(ua) - xd0;
        d0 *= d0;
        float d1 = bfhi(ua) - xd1;
        d1 *= d1;
        s0 += d0;
        q0 += d0 * d0;
        s1 += d1;
        q1 += d1 * d1;
      }
    }
  }
  pS[w][2 * l] = s0;
  pS[w][2 * l + 1] = s1;
  pQ[w][2 * l] = q0;
  pQ[w][2 * l + 1] = q1;
  __syncthreads();
  if (t < 128) {
    atomicAdd(&stat[t], pS[0][t] + pS[1][t] + pS[2][t] + pS[3][t]);
  } else {
    const int c = t - 128;
    atomicAdd(&stat[128 + c], pQ[0][c] + pQ[1][c] + pQ[2][c] + pQ[3][c]);
  }
}

// ---------------------------------------------------------------------------
// node_scores with fused att computation: every block recomputes the att
// vectors from stat (tiny, deterministic), then streams per-node dots.
// ---------------------------------------------------------------------------
__global__ __launch_bounds__(256) void node_scores_att(
    const float* __restrict__ X, const float* __restrict__ stat,
    const float* __restrict__ src_w, const float* __restrict__ src_b,
    const float* __restrict__ dst_w, const float* __restrict__ dst_b,
    const float* __restrict__ tq, float* __restrict__ a_src,
    float* __restrict__ a_dst, int n, float Ef) {
  __shared__ float red[4][128];
  __shared__ float attL[128];
  __shared__ float attR[128];
  const int t = threadIdx.x;
  float S[4];
  if (t < 128) {
    const int c = t;
    const float sum = stat[c], sq = stat[128 + c];
    const float m1 = sum / Ef;
    float var = (sq - sum * (sum / Ef)) / (Ef - 1.0f);
    var = fmaxf(var, 0.0f);
    const float sd = sqrtf(var);
    const float m2 = sd + 1e-5f;
    S[0] = m1;
    S[1] = sd;
    S[2] = (m1 * m1 * m1) / (m2 * m2 * m2);
    const float m12 = m1 * m1, m22 = m2 * m2;
    S[3] = (m12 * m12) / (m22 * m22);
#pragma unroll
    for (int j = 0; j < 4; j++) {
      if (isnan(S[j])) S[j] = 0.0f;
      S[j] = tanhf(S[j]);
      red[j][c] = S[j] * S[j];
    }
  }
  for (int o = 64; o; o >>= 1) {
    __syncthreads();
    if (t < o) {
#pragma unroll
      for (int j = 0; j < 4; j++) red[j][t] += red[j][t + o];
    }
  }
  __syncthreads();
  if (t < 128) {
#pragma unroll
    for (int j = 0; j < 4; j++) S[j] /= fmaxf(sqrtf(red[j][0]), 1e-12f);
    float al = 0.0f, ar = 0.0f;
#pragma unroll
    for (int j = 0; j < 16; j++) {
      float tl = src_b[j], tr = dst_b[j];
#pragma unroll
      for (int k = 0; k < 4; k++) {
        tl += S[k] * src_w[j * 4 + k];
        tr += S[k] * dst_w[j * 4 + k];
      }
      al += tq[j] * tl;
      ar += tq[j] * tr;
    }
    attL[t] = al;
    attR[t] = ar;
  }
  __syncthreads();
  const int l = t & 63;
  const float2 al2 = make_float2(attL[2 * l], attL[2 * l + 1]);
  const float2 ar2 = make_float2(attR[2 * l], attR[2 * l + 1]);
  const int wid = blockIdx.x * 4 + (t >> 6);
  const int nw = gridDim.x * 4;
  for (int i = wid; i < n; i += nw) {
    const float2 xv = ((const float2*)(X + (long)i * 128))[l];
    float sl = xv.x * al2.x + xv.y * al2.y;
    float sr = xv.x * ar2.x + xv.y * ar2.y;
    sl = wave_sum(sl);
    sr = wave_sum(sr);
    if (l == 0) {
      a_src[i] = sl;
      a_dst[i] = sr;
    }
  }
}

// ---------------------------------------------------------------------------
// CSR build (by dst, self-loops included via deg init = 1)
// init_deg also zeroes stat (for layer 0).
// ---------------------------------------------------------------------------
__global__ void init_deg(int* deg, int n, float* stat) {
  int i = blockIdx.x * 256 + threadIdx.x;
  if (i < n) deg[i] = 1;
  if (i < 256) stat[i] = 0.0f;
}
__global__ void hist_dst(const int* __restrict__ edst, int E, int* deg) {
  int e = blockIdx.x * 256 + threadIdx.x;
  if (e < E) atomicAdd(&deg[edst[e]], 1);
}
__global__ __launch_bounds__(256) void scan_partial(const int* __restrict__ deg,
                                                    int n, int* bsum) {
  __shared__ int r[256];
  int t = threadIdx.x;
  int g = blockIdx.x * 256 + t;
  r[t] = (g < n) ? deg[g] : 0;
  for (int o = 128; o; o >>= 1) {
    __syncthreads();
    if (t < o) r[t] += r[t + o];
  }
  if (t == 0) bsum[blockIdx.x] = r[0];
}
__global__ __launch_bounds__(256) void scan_bsums(int* bsum, int nb) {
  __shared__ int r[256];
  int t = threadIdx.x;
  int v = (t < nb) ? bsum[t] : 0;
  r[t] = v;
  for (int o = 1; o < 256; o <<= 1) {
    int x = 0;
    __syncthreads();
    if (t >= o) x = r[t - o];
    __syncthreads();
    r[t] += x;
  }
  if (t < nb) bsum[t] = r[t] - v;  // exclusive
}
__global__ __launch_bounds__(256) void scan_final(const int* __restrict__ deg,
                                                  int n,
                                                  const int* __restrict__ bsum,
                                                  int* offs, int* cursor) {
  __shared__ int r[256];
  int t = threadIdx.x;
  int g = blockIdx.x * 256 + t;
  int v = (g < n) ? deg[g] : 0;
  r[t] = v;
  for (int o = 1; o < 256; o <<= 1) {
    int x = 0;
    __syncthreads();
    if (t >= o) x = r[t - o];
    __syncthreads();
    r[t] += x;
  }
  int excl = bsum[blockIdx.x] + r[t] - v;
  if (g < n) {
    offs[g] = excl;
    cursor[g] = excl;
    if (g == n - 1) offs[n] = excl + v;
  }
}
__global__ void scatter_csr(const int* __restrict__ esrc,
                            const int* __restrict__ edst, int E, int n,
                            int* cursor, int* __restrict__ csr) {
  int g = blockIdx.x * 256 + threadIdx.x;
  if (g < E) {
    int d = edst[g];
    int p = atomicAdd(&cursor[d], 1);
    csr[p] = esrc[g];
  } else if (g < E + n) {
    int i = g - E;
    int p = atomicAdd(&cursor[i], 1);
    csr[p] = i;
  }
}

// ---------------------------------------------------------------------------
// Softmax aggregation, bf16 gather, unroll-8, edge-balanced node ranges.
// Also zeroes stat (block 0) for the NEXT stats dispatch.
// ---------------------------------------------------------------------------
__global__ __launch_bounds__(256) void aggregate_bf(
    const unsigned* __restrict__ Xb, const int* __restrict__ csr,
    const int* __restrict__ offs, const float* __restrict__ a_src,
    const float* __restrict__ a_dst, const float* __restrict__ bias,
    float* __restrict__ Y, unsigned* __restrict__ Yb, int n, int T,
    int do_relu, int write_bf, float* __restrict__ stat_zero) {
  if (blockIdx.x == 0 && threadIdx.x < 256) stat_zero[threadIdx.x] = 0.0f;
  const int t = threadIdx.x;
  const int l = t & 63;
  const int wave = blockIdx.x * 4 + (t >> 6);
  const int key0 = wave * T;
  const int key1 = key0 + T;
  const float2 b2 = ((const float2*)bias)[l];
  for (int i = lb_offs(offs, n, key0); i < n; ++i) {
    const int beg = offs[i];
    if (beg >= key1) break;
    const int end = offs[i + 1];
    const int deg = end - beg;
    const float adsti = a_dst[i];
    float ax = 0.0f, ay = 0.0f;
    if (deg <= 128) {
      int s0r = 0, s1r = 0;
      float a0 = -INFINITY, a1 = -INFINITY;
      if (l < deg) {
        s0r = csr[beg + l];
        float a = a_src[s0r] + adsti;
        a0 = (a > 0.0f ? a : 0.2f * a) * 0.1f;
      }
      if (64 + l < deg) {
        s1r = csr[beg + 64 + l];
        float a = a_src[s1r] + adsti;
        a1 = (a > 0.0f ? a : 0.2f * a) * 0.1f;
      }
      const float mx = wave_max(fmaxf(a0, a1));
      const float e0 = expf(a0 - mx);  // exp(-inf - mx) = 0 for idle lanes
      const float e1 = expf(a1 - mx);
      const float sm = wave_sum(e0 + e1);
      const float inv = 1.0f / (sm + 1e-16f);
      const float al0 = e0 * inv, al1 = e1 * inv;
      int k = 0;
      for (; k + 8 <= deg; k += 8) {
        int sx[8];
        float wv[8];
#pragma unroll
        for (int j = 0; j < 8; j++) {
          const int kk = k + j;
          sx[j] = __shfl(kk < 64 ? s0r : s1r, kk & 63);
          wv[j] = __shfl(kk < 64 ? al0 : al1, kk & 63);
        }
        unsigned ua[8];
#pragma unroll
        for (int j = 0; j < 8; j++) ua[j] = Xb[(long)sx[j] * 64 + l];
#pragma unroll
        for (int j = 0; j < 8; j++) {
          ax = fmaf(wv[j], bflo(ua[j]), ax);
          ay = fmaf(wv[j], bfhi(ua[j]), ay);
        }
      }
      for (; k < deg; ++k) {
        const int s = __shfl(k < 64 ? s0r : s1r, k & 63);
        const float w = __shfl(k < 64 ? al0 : al1, k & 63);
        const unsigned ua = Xb[(long)s * 64 + l];
        ax = fmaf(w, bflo(ua), ax);
        ay = fmaf(w, bfhi(ua), ay);
      }
    } else {
      float mx = -1e30f;
      for (int p = beg + l; p < end; p += 64) {
        float a = a_src[csr[p]] + adsti;
        a = (a > 0.0f ? a : 0.2f * a) * 0.1f;
        mx = fmaxf(mx, a);
      }
      mx = wave_max(mx);
      float sm = 0.0f;
      for (int p = beg + l; p < end; p += 64) {
        float a = a_src[csr[p]] + adsti;
        a = (a > 0.0f ? a : 0.2f * a) * 0.1f;
        sm += expf(a - mx);
      }
      sm = wave_sum(sm);
      const float inv = 1.0f / (sm + 1e-16f);
      for (int p = beg; p < end; ++p) {
        const int s = csr[p];
        float a = a_src[s] + adsti;
        a = (a > 0.0f ? a : 0.2f * a) * 0.1f;
        const float alpha = expf(a - mx) * inv;
        const unsigned ua = Xb[(long)s * 64 + l];
        ax = fmaf(alpha, bflo(ua), ax);
        ay = fmaf(alpha, bfhi(ua), ay);
      }
    }
    float ox = ax + b2.x, oy = ay + b2.y;
    if (do_relu) {
      ox = fmaxf(ox, 0.0f);
      oy = fmaxf(oy, 0.0f);
    }
    ((float2*)(Y + (long)i * 128))[l] = make_float2(ox, oy);
    if (write_bf) Yb[(long)i * 64 + l] = packbf(ox, oy);
  }
}

// ---------------------------------------------------------------------------
extern "C" void kernel_launch(void* const* d_in, const int* in_sizes, int n_in,
                              void* d_out, int out_size, void* d_ws,
                              size_t ws_size, hipStream_t stream) {
  (void)n_in;
  (void)out_size;
  (void)ws_size;
  const float* x = (const float*)d_in[0];
  const int* ei = (const int*)d_in[1];
  const float* W0 = (const float*)d_in[2];
  const float* b0 = (const float*)d_in[3];
  const float* W2 = (const float*)d_in[4];
  const float* b2 = (const float*)d_in[5];
  const float* gsw[2] = {(const float*)d_in[6], (const float*)d_in[12]};
  const float* gsb[2] = {(const float*)d_in[7], (const float*)d_in[13]};
  const float* gdw[2] = {(const float*)d_in[8], (const float*)d_in[14]};
  const float* gdb[2] = {(const float*)d_in[9], (const float*)d_in[15]};
  const float* gtq[2] = {(const float*)d_in[10], (const float*)d_in[16]};
  const float* gbias[2] = {(const float*)d_in[11], (const float*)d_in[17]};

  const int N = in_sizes[0] / 128;
  const int E = in_sizes[1] / 2;
  const int* esrc = ei;
  const int* edst = ei + E;

  float* ws = (float*)d_ws;
  size_t o = 0;
  float* h0 = ws + o;
  o += (size_t)N * 128;
  float* h1 = ws + o;
  o += (size_t)N * 128;
  unsigned* h0b = (unsigned*)(ws + o);
  o += (size_t)N * 64;
  unsigned* h1b = (unsigned*)(ws + o);
  o += (size_t)N * 64;
  float* stat = ws + o;
  o += 256;
  float* a_src = ws + o;
  o += N;
  float* a_dst = ws + o;
  o += N;
  int* ip = (int*)(ws + o);
  int* deg = ip;
  ip += N;
  int* offs = ip;
  ip += N + 1;
  int* cursor = ip;
  ip += N;
  int* bsum = ip;
  ip += 256;
  int* csr = ip;
  ip += E + N;

  const int NB = (N + 255) / 256;  // 196 <= 256 required by scan_bsums

  const int GATHER_BLOCKS = 2048;
  const int NWAVES = GATHER_BLOCKS * 4;
  const int T = (E + N + NWAVES - 1) / NWAVES;  // edges per wave target

  // GEMM1: h0 = x @ W0^T + b0  (+ bf16 shadow h0b)
  gemm_bias<128, true><<<(N + 127) / 128, 256, 0, stream>>>(x, W0, b0, h0,
                                                            h0b, N);

  // CSR build (shared by both convs); init_deg also zeroes stat
  init_deg<<<NB, 256, 0, stream>>>(deg, N, stat);
  hist_dst<<<(E + 255) / 256, 256, 0, stream>>>(edst, E, deg);
  scan_partial<<<NB, 256, 0, stream>>>(deg, N, bsum);
  scan_bsums<<<1, 256, 0, stream>>>(bsum, NB);
  scan_final<<<NB, 256, 0, stream>>>(deg, N, bsum, offs, cursor);
  scatter_csr<<<(E + N + 255) / 256, 256, 0, stream>>>(esrc, edst, E, N,
                                                       cursor, csr);

  for (int layer = 0; layer < 2; ++layer) {
    const float* Xf = layer ? h1 : h0;
    const unsigned* Xb = layer ? h1b : h0b;
    float* Yf = layer ? h0 : h1;
    unsigned* Yb = layer ? h0b : h1b;  // only written for layer 0
    edge_stats_bf<<<GATHER_BLOCKS, 256, 0, stream>>>(Xb, csr, offs, N, T,
                                                     stat);
    node_scores_att<<<1024, 256, 0, stream>>>(
        Xf, stat, gsw[layer], gsb[layer], gdw[layer], gdb[layer], gtq[layer],
        a_src, a_dst, N, (float)E);
    aggregate_bf<<<GATHER_BLOCKS, 256, 0, stream>>>(
        Xb, csr, offs, a_src, a_dst, gbias[layer], Yf, Yb, N, T,
        layer == 0 ? 1 : 0, layer == 0 ? 1 : 0, stat);
  }

  // GEMM2: out = h0 @ W2^T + b2   (h0 holds conv2 output, fp32)
  gemm_bias<64, false><<<(N + 127) / 128, 256, 0, stream>>>(
      h0, W2, b2, (float*)d_out, nullptr, N);
}

// Round 8
// 510.721 us; speedup vs baseline: 1.0666x; 1.0630x over previous
//
#include <hip/hip_runtime.h>
#include <math.h>

// ---------------------------------------------------------------------------
// SPA graph conv, 2 layers. N=50000, E=800000, C=128, OUT=64, HS=16, K=4.
// R8: gather kernels back to the proven R5 structure (unroll-4, grid-stride;
//     R7's unroll-8 + binsearch regressed). NEW: fp8(e4m3) shadow table for
//     the STATS gather only (6.4MB -> mostly L2-resident per XCD, half the
//     bytes). Aggregate keeps bf16 (output accuracy budget). Producers write
//     bf16 + fp8 shadows. Dispatch fusions from R7 kept (fused att+scores,
//     stat zeroing folded into other kernels).
// ---------------------------------------------------------------------------

__device__ __forceinline__ float wave_max(float v) {
#pragma unroll
  for (int o = 32; o; o >>= 1) v = fmaxf(v, __shfl_xor(v, o, 64));
  return v;
}
__device__ __forceinline__ float wave_sum(float v) {
#pragma unroll
  for (int o = 32; o; o >>= 1) v += __shfl_xor(v, o, 64);
  return v;
}

// bf16 pair packed in a uint: low ushort = even channel, high = odd channel.
__device__ __forceinline__ float bflo(unsigned u) {
  return __uint_as_float(u << 16);
}
__device__ __forceinline__ float bfhi(unsigned u) {
  return __uint_as_float(u & 0xffff0000u);
}
__device__ __forceinline__ unsigned f2bf(float f) {  // RNE
  unsigned x = __float_as_uint(f);
  return (x + 0x7fffu + ((x >> 16) & 1u)) >> 16;
}
__device__ __forceinline__ unsigned packbf(float a, float b) {
  return f2bf(a) | (f2bf(b) << 16);
}

// fp8 e4m3 decode (byte sel 0/1 of a uint) and pack (2 floats -> 2 bytes)
__device__ __forceinline__ float fp8lo(unsigned u) {
  return __builtin_amdgcn_cvt_f32_fp8(u, 0);
}
__device__ __forceinline__ float fp8hi(unsigned u) {
  return __builtin_amdgcn_cvt_f32_fp8(u, 1);
}
__device__ __forceinline__ unsigned short pk_fp8_pair(float a, float b) {
  return (unsigned short)(__builtin_amdgcn_cvt_pk_fp8_f32(a, b, 0, false) &
                          0xffff);
}

// ---------------------------------------------------------------------------
// GEMM: Y[r][c] = sum_k X[r][k]*W[c][k] + bias[c].  K fixed = 128.
// BFOUT: also write bf16 shadow (uint = 2ch) and fp8 shadow (byte = 1ch).
// ---------------------------------------------------------------------------
template <int COLS, bool BFOUT>
__global__ __launch_bounds__(256) void gemm_bias(
    const float* __restrict__ X, const float* __restrict__ W,
    const float* __restrict__ bias, float* __restrict__ Y,
    unsigned* __restrict__ Yb, unsigned char* __restrict__ Y8, int nrows) {
  __shared__ float Wt[128 * COLS];
  const int t = threadIdx.x;
  for (int q = t; q < COLS * 32; q += 256) {
    const int c = q >> 5;
    const int k0 = (q & 31) << 2;
    const float4 w = *(const float4*)(W + c * 128 + k0);
    Wt[(k0 + 0) * COLS + c] = w.x;
    Wt[(k0 + 1) * COLS + c] = w.y;
    Wt[(k0 + 2) * COLS + c] = w.z;
    Wt[(k0 + 3) * COLS + c] = w.w;
  }
  __syncthreads();
  const int tx = t & 15, ty = t >> 4;
  const long rbase = (long)blockIdx.x * 128 + ty * 8;
  constexpr int NG = COLS / 64;
  float acc[8][NG * 4];
#pragma unroll
  for (int i = 0; i < 8; i++)
#pragma unroll
    for (int j = 0; j < NG * 4; j++) acc[i][j] = 0.0f;
  const float* xp[8];
#pragma unroll
  for (int i = 0; i < 8; i++) {
    long r = rbase + i;
    if (r > nrows - 1) r = nrows - 1;
    xp[i] = X + r * 128;
  }
  for (int k0 = 0; k0 < 128; k0 += 4) {
    float4 xv[8];
#pragma unroll
    for (int i = 0; i < 8; i++) xv[i] = *(const float4*)(xp[i] + k0);
#pragma unroll
    for (int kk = 0; kk < 4; kk++) {
      float4 wv[NG];
#pragma unroll
      for (int g = 0; g < NG; g++)
        wv[g] = *(const float4*)(&Wt[(k0 + kk) * COLS + g * 64 + 4 * tx]);
#pragma unroll
      for (int i = 0; i < 8; i++) {
        const float xs = ((const float*)&xv[i])[kk];
#pragma unroll
        for (int g = 0; g < NG; g++) {
          acc[i][g * 4 + 0] = fmaf(xs, wv[g].x, acc[i][g * 4 + 0]);
          acc[i][g * 4 + 1] = fmaf(xs, wv[g].y, acc[i][g * 4 + 1]);
          acc[i][g * 4 + 2] = fmaf(xs, wv[g].z, acc[i][g * 4 + 2]);
          acc[i][g * 4 + 3] = fmaf(xs, wv[g].w, acc[i][g * 4 + 3]);
        }
      }
    }
  }
  float4 bv[NG];
#pragma unroll
  for (int g = 0; g < NG; g++) bv[g] = *(const float4*)(bias + g * 64 + 4 * tx);
#pragma unroll
  for (int i = 0; i < 8; i++) {
    const long r = rbase + i;
    if (r < nrows) {
#pragma unroll
      for (int g = 0; g < NG; g++) {
        float4 o;
        o.x = acc[i][g * 4 + 0] + bv[g].x;
        o.y = acc[i][g * 4 + 1] + bv[g].y;
        o.z = acc[i][g * 4 + 2] + bv[g].z;
        o.w = acc[i][g * 4 + 3] + bv[g].w;
        const int c = g * 64 + 4 * tx;
        *(float4*)(Y + r * COLS + c) = o;
        if (BFOUT) {
          uint2 p;
          p.x = packbf(o.x, o.y);
          p.y = packbf(o.z, o.w);
          *(uint2*)(Yb + r * (COLS / 2) + (c >> 1)) = p;
          unsigned w8 = __builtin_amdgcn_cvt_pk_fp8_f32(o.x, o.y, 0, false);
          w8 = __builtin_amdgcn_cvt_pk_fp8_f32(o.z, o.w, w8, true);
          ((unsigned*)(Y8 + (long)r * COLS))[c >> 2] = w8;
        }
      }
    }
  }
}

// ---------------------------------------------------------------------------
// Edge moment stats via CSR, fp8 gather (ushort/lane = 2 channels, 128B/row).
// R5 structure: wave per dst node, grid-stride, unroll-4 indep loads,
// (src) indices broadcast from registers. Self-loops contribute 0; Ef=E.
// ---------------------------------------------------------------------------
__global__ __launch_bounds__(256) void edge_stats_f8(
    const unsigned char* __restrict__ X8, const int* __restrict__ csr,
    const int* __restrict__ offs, int n, float* __restrict__ stat) {
  __shared__ float pS[4][128];
  __shared__ float pQ[4][128];
  const unsigned short* __restrict__ X16 = (const unsigned short*)X8;
  const int t = threadIdx.x;
  const int w = t >> 6, l = t & 63;
  const int wid = blockIdx.x * 4 + w;
  const int nw = gridDim.x * 4;
  float s0 = 0.f, q0 = 0.f, s1 = 0.f, q1 = 0.f;
  for (int i = wid; i < n; i += nw) {
    const int beg = offs[i], end = offs[i + 1];
    const int deg = end - beg;
    const unsigned ud = X16[(long)i * 64 + l];
    const float xd0 = fp8lo(ud), xd1 = fp8hi(ud);
    if (deg <= 128) {
      int s0r = 0, s1r = 0;
      if (l < deg) s0r = csr[beg + l];
      if (64 + l < deg) s1r = csr[beg + 64 + l];
      int k = 0;
      for (; k + 4 <= deg; k += 4) {
        int sx[4];
#pragma unroll
        for (int j = 0; j < 4; j++) {
          const int kk = k + j;
          sx[j] = __shfl(kk < 64 ? s0r : s1r, kk & 63);
        }
        unsigned ua[4];
#pragma unroll
        for (int j = 0; j < 4; j++) ua[j] = X16[(long)sx[j] * 64 + l];
#pragma unroll
        for (int j = 0; j < 4; j++) {
          float d0 = fp8lo(ua[j]) - xd0;
          d0 *= d0;
          float d1 = fp8hi(ua[j]) - xd1;
          d1 *= d1;
          s0 += d0;
          q0 += d0 * d0;
          s1 += d1;
          q1 += d1 * d1;
        }
      }
      for (; k < deg; ++k) {
        const int s = __shfl(k < 64 ? s0r : s1r, k & 63);
        const unsigned ua = X16[(long)s * 64 + l];
        float d0 = fp8lo(ua) - xd0;
        d0 *= d0;
        float d1 = fp8hi(ua) - xd1;
        d1 *= d1;
        s0 += d0;
        q0 += d0 * d0;
        s1 += d1;
        q1 += d1 * d1;
      }
    } else {
      for (int p = beg; p < end; ++p) {
        const int s = csr[p];
        const unsigned ua = X16[(long)s * 64 + l];
        float d0 = fp8lo(ua) - xd0;
        d0 *= d0;
        float d1 = fp8hi(ua) - xd1;
        d1 *= d1;
        s0 += d0;
        q0 += d0 * d0;
        s1 += d1;
        q1 += d1 * d1;
      }
    }
  }
  pS[w][2 * l] = s0;
  pS[w][2 * l + 1] = s1;
  pQ[w][2 * l] = q0;
  pQ[w][2 * l + 1] = q1;
  __syncthreads();
  if (t < 128) {
    atomicAdd(&stat[t], pS[0][t] + pS[1][t] + pS[2][t] + pS[3][t]);
  } else {
    const int c = t - 128;
    atomicAdd(&stat[128 + c], pQ[0][c] + pQ[1][c] + pQ[2][c] + pQ[3][c]);
  }
}

// ---------------------------------------------------------------------------
// node_scores with fused att computation: every block recomputes the att
// vectors from stat (tiny, deterministic), then streams per-node dots.
// ---------------------------------------------------------------------------
__global__ __launch_bounds__(256) void node_scores_att(
    const float* __restrict__ X, const float* __restrict__ stat,
    const float* __restrict__ src_w, const float* __restrict__ src_b,
    const float* __restrict__ dst_w, const float* __restrict__ dst_b,
    const float* __restrict__ tq, float* __restrict__ a_src,
    float* __restrict__ a_dst, int n, float Ef) {
  __shared__ float red[4][128];
  __shared__ float attL[128];
  __shared__ float attR[128];
  const int t = threadIdx.x;
  float S[4];
  if (t < 128) {
    const int c = t;
    const float sum = stat[c], sq = stat[128 + c];
    const float m1 = sum / Ef;
    float var = (sq - sum * (sum / Ef)) / (Ef - 1.0f);
    var = fmaxf(var, 0.0f);
    const float sd = sqrtf(var);
    const float m2 = sd + 1e-5f;
    S[0] = m1;
    S[1] = sd;
    S[2] = (m1 * m1 * m1) / (m2 * m2 * m2);
    const float m12 = m1 * m1, m22 = m2 * m2;
    S[3] = (m12 * m12) / (m22 * m22);
#pragma unroll
    for (int j = 0; j < 4; j++) {
      if (isnan(S[j])) S[j] = 0.0f;
      S[j] = tanhf(S[j]);
      red[j][c] = S[j] * S[j];
    }
  }
  for (int o = 64; o; o >>= 1) {
    __syncthreads();
    if (t < o) {
#pragma unroll
      for (int j = 0; j < 4; j++) red[j][t] += red[j][t + o];
    }
  }
  __syncthreads();
  if (t < 128) {
#pragma unroll
    for (int j = 0; j < 4; j++) S[j] /= fmaxf(sqrtf(red[j][0]), 1e-12f);
    float al = 0.0f, ar = 0.0f;
#pragma unroll
    for (int j = 0; j < 16; j++) {
      float tl = src_b[j], tr = dst_b[j];
#pragma unroll
      for (int k = 0; k < 4; k++) {
        tl += S[k] * src_w[j * 4 + k];
        tr += S[k] * dst_w[j * 4 + k];
      }
      al += tq[j] * tl;
      ar += tq[j] * tr;
    }
    attL[t] = al;
    attR[t] = ar;
  }
  __syncthreads();
  const int l = t & 63;
  const float2 al2 = make_float2(attL[2 * l], attL[2 * l + 1]);
  const float2 ar2 = make_float2(attR[2 * l], attR[2 * l + 1]);
  const int wid = blockIdx.x * 4 + (t >> 6);
  const int nw = gridDim.x * 4;
  for (int i = wid; i < n; i += nw) {
    const float2 xv = ((const float2*)(X + (long)i * 128))[l];
    float sl = xv.x * al2.x + xv.y * al2.y;
    float sr = xv.x * ar2.x + xv.y * ar2.y;
    sl = wave_sum(sl);
    sr = wave_sum(sr);
    if (l == 0) {
      a_src[i] = sl;
      a_dst[i] = sr;
    }
  }
}

// ---------------------------------------------------------------------------
// CSR build (by dst, self-loops included via deg init = 1)
// init_deg also zeroes stat (for layer 0).
// ---------------------------------------------------------------------------
__global__ void init_deg(int* deg, int n, float* stat) {
  int i = blockIdx.x * 256 + threadIdx.x;
  if (i < n) deg[i] = 1;
  if (i < 256) stat[i] = 0.0f;
}
__global__ void hist_dst(const int* __restrict__ edst, int E, int* deg) {
  int e = blockIdx.x * 256 + threadIdx.x;
  if (e < E) atomicAdd(&deg[edst[e]], 1);
}
__global__ __launch_bounds__(256) void scan_partial(const int* __restrict__ deg,
                                                    int n, int* bsum) {
  __shared__ int r[256];
  int t = threadIdx.x;
  int g = blockIdx.x * 256 + t;
  r[t] = (g < n) ? deg[g] : 0;
  for (int o = 128; o; o >>= 1) {
    __syncthreads();
    if (t < o) r[t] += r[t + o];
  }
  if (t == 0) bsum[blockIdx.x] = r[0];
}
__global__ __launch_bounds__(256) void scan_bsums(int* bsum, int nb) {
  __shared__ int r[256];
  int t = threadIdx.x;
  int v = (t < nb) ? bsum[t] : 0;
  r[t] = v;
  for (int o = 1; o < 256; o <<= 1) {
    int x = 0;
    __syncthreads();
    if (t >= o) x = r[t - o];
    __syncthreads();
    r[t] += x;
  }
  if (t < nb) bsum[t] = r[t] - v;  // exclusive
}
__global__ __launch_bounds__(256) void scan_final(const int* __restrict__ deg,
                                                  int n,
                                                  const int* __restrict__ bsum,
                                                  int* offs, int* cursor) {
  __shared__ int r[256];
  int t = threadIdx.x;
  int g = blockIdx.x * 256 + t;
  int v = (g < n) ? deg[g] : 0;
  r[t] = v;
  for (int o = 1; o < 256; o <<= 1) {
    int x = 0;
    __syncthreads();
    if (t >= o) x = r[t - o];
    __syncthreads();
    r[t] += x;
  }
  int excl = bsum[blockIdx.x] + r[t] - v;
  if (g < n) {
    offs[g] = excl;
    cursor[g] = excl;
    if (g == n - 1) offs[n] = excl + v;
  }
}
__global__ void scatter_csr(const int* __restrict__ esrc,
                            const int* __restrict__ edst, int E, int n,
                            int* cursor, int* __restrict__ csr) {
  int g = blockIdx.x * 256 + threadIdx.x;
  if (g < E) {
    int d = edst[g];
    int p = atomicAdd(&cursor[d], 1);
    csr[p] = esrc[g];
  } else if (g < E + n) {
    int i = g - E;
    int p = atomicAdd(&cursor[i], 1);
    csr[p] = i;
  }
}

// ---------------------------------------------------------------------------
// Softmax aggregation, bf16 gather (R5 structure: wave per node, grid-stride,
// lane-parallel softmax, register-broadcast serial accumulate, unroll-4).
// Layer 0 also writes bf16 + fp8 shadows of its output; zeroes stat for the
// next stats dispatch (block 0).
// ---------------------------------------------------------------------------
__global__ __launch_bounds__(256) void aggregate_bf(
    const unsigned* __restrict__ Xb, const int* __restrict__ csr,
    const int* __restrict__ offs, const float* __restrict__ a_src,
    const float* __restrict__ a_dst, const float* __restrict__ bias,
    float* __restrict__ Y, unsigned* __restrict__ Yb,
    unsigned char* __restrict__ Y8, int n, int do_relu, int write_shadow,
    float* __restrict__ stat_zero) {
  if (blockIdx.x == 0 && threadIdx.x < 256) stat_zero[threadIdx.x] = 0.0f;
  const int t = threadIdx.x;
  const int l = t & 63;
  const int wid = blockIdx.x * 4 + (t >> 6);
  const int nw = gridDim.x * 4;
  const float2 b2 = ((const float2*)bias)[l];
  for (int i = wid; i < n; i += nw) {
    const int beg = offs[i], end = offs[i + 1];
    const int deg = end - beg;
    const float adsti = a_dst[i];
    float ax = 0.0f, ay = 0.0f;
    if (deg <= 128) {
      int s0r = 0, s1r = 0;
      float a0 = -INFINITY, a1 = -INFINITY;
      if (l < deg) {
        s0r = csr[beg + l];
        float a = a_src[s0r] + adsti;
        a0 = (a > 0.0f ? a : 0.2f * a) * 0.1f;
      }
      if (64 + l < deg) {
        s1r = csr[beg + 64 + l];
        float a = a_src[s1r] + adsti;
        a1 = (a > 0.0f ? a : 0.2f * a) * 0.1f;
      }
      const float mx = wave_max(fmaxf(a0, a1));
      const float e0 = expf(a0 - mx);  // exp(-inf - mx) = 0 for idle lanes
      const float e1 = expf(a1 - mx);
      const float sm = wave_sum(e0 + e1);
      const float inv = 1.0f / (sm + 1e-16f);
      const float al0 = e0 * inv, al1 = e1 * inv;
      int k = 0;
      for (; k + 4 <= deg; k += 4) {
        int sx[4];
        float wv[4];
#pragma unroll
        for (int j = 0; j < 4; j++) {
          const int kk = k + j;
          sx[j] = __shfl(kk < 64 ? s0r : s1r, kk & 63);
          wv[j] = __shfl(kk < 64 ? al0 : al1, kk & 63);
        }
        unsigned ua[4];
#pragma unroll
        for (int j = 0; j < 4; j++) ua[j] = Xb[(long)sx[j] * 64 + l];
#pragma unroll
        for (int j = 0; j < 4; j++) {
          ax = fmaf(wv[j], bflo(ua[j]), ax);
          ay = fmaf(wv[j], bfhi(ua[j]), ay);
        }
      }
      for (; k < deg; ++k) {
        const int s = __shfl(k < 64 ? s0r : s1r, k & 63);
        const float w = __shfl(k < 64 ? al0 : al1, k & 63);
        const unsigned ua = Xb[(long)s * 64 + l];
        ax = fmaf(w, bflo(ua), ax);
        ay = fmaf(w, bfhi(ua), ay);
      }
    } else {
      float mx = -1e30f;
      for (int p = beg + l; p < end; p += 64) {
        float a = a_src[csr[p]] + adsti;
        a = (a > 0.0f ? a : 0.2f * a) * 0.1f;
        mx = fmaxf(mx, a);
      }
      mx = wave_max(mx);
      float sm = 0.0f;
      for (int p = beg + l; p < end; p += 64) {
        float a = a_src[csr[p]] + adsti;
        a = (a > 0.0f ? a : 0.2f * a) * 0.1f;
        sm += expf(a - mx);
      }
      sm = wave_sum(sm);
      const float inv = 1.0f / (sm + 1e-16f);
      for (int p = beg; p < end; ++p) {
        const int s = csr[p];
        float a = a_src[s] + adsti;
        a = (a > 0.0f ? a : 0.2f * a) * 0.1f;
        const float alpha = expf(a - mx) * inv;
        const unsigned ua = Xb[(long)s * 64 + l];
        ax = fmaf(alpha, bflo(ua), ax);
        ay = fmaf(alpha, bfhi(ua), ay);
      }
    }
    float ox = ax + b2.x, oy = ay + b2.y;
    if (do_relu) {
      ox = fmaxf(ox, 0.0f);
      oy = fmaxf(oy, 0.0f);
    }
    ((float2*)(Y + (long)i * 128))[l] = make_float2(ox, oy);
    if (write_shadow) {
      Yb[(long)i * 64 + l] = packbf(ox, oy);
      ((unsigned short*)Y8)[(long)i * 64 + l] = pk_fp8_pair(ox, oy);
    }
  }
}

// ---------------------------------------------------------------------------
extern "C" void kernel_launch(void* const* d_in, const int* in_sizes, int n_in,
                              void* d_out, int out_size, void* d_ws,
                              size_t ws_size, hipStream_t stream) {
  (void)n_in;
  (void)out_size;
  (void)ws_size;
  const float* x = (const float*)d_in[0];
  const int* ei = (const int*)d_in[1];
  const float* W0 = (const float*)d_in[2];
  const float* b0 = (const float*)d_in[3];
  const float* W2 = (const float*)d_in[4];
  const float* b2 = (const float*)d_in[5];
  const float* gsw[2] = {(const float*)d_in[6], (const float*)d_in[12]};
  const float* gsb[2] = {(const float*)d_in[7], (const float*)d_in[13]};
  const float* gdw[2] = {(const float*)d_in[8], (const float*)d_in[14]};
  const float* gdb[2] = {(const float*)d_in[9], (const float*)d_in[15]};
  const float* gtq[2] = {(const float*)d_in[10], (const float*)d_in[16]};
  const float* gbias[2] = {(const float*)d_in[11], (const float*)d_in[17]};

  const int N = in_sizes[0] / 128;
  const int E = in_sizes[1] / 2;
  const int* esrc = ei;
  const int* edst = ei + E;

  float* ws = (float*)d_ws;
  size_t o = 0;
  float* h0 = ws + o;
  o += (size_t)N * 128;
  float* h1 = ws + o;
  o += (size_t)N * 128;
  unsigned* h0b = (unsigned*)(ws + o);
  o += (size_t)N * 64;
  unsigned* h1b = (unsigned*)(ws + o);
  o += (size_t)N * 64;
  unsigned char* h0f8 = (unsigned char*)(ws + o);
  o += (size_t)N * 32;
  unsigned char* h1f8 = (unsigned char*)(ws + o);
  o += (size_t)N * 32;
  float* stat = ws + o;
  o += 256;
  float* a_src = ws + o;
  o += N;
  float* a_dst = ws + o;
  o += N;
  int* ip = (int*)(ws + o);
  int* deg = ip;
  ip += N;
  int* offs = ip;
  ip += N + 1;
  int* cursor = ip;
  ip += N;
  int* bsum = ip;
  ip += 256;
  int* csr = ip;
  ip += E + N;

  const int NB = (N + 255) / 256;  // 196 <= 256 required by scan_bsums

  // GEMM1: h0 = x @ W0^T + b0  (+ bf16 shadow h0b, fp8 shadow h0f8)
  gemm_bias<128, true><<<(N + 127) / 128, 256, 0, stream>>>(x, W0, b0, h0,
                                                            h0b, h0f8, N);

  // CSR build (shared by both convs); init_deg also zeroes stat
  init_deg<<<NB, 256, 0, stream>>>(deg, N, stat);
  hist_dst<<<(E + 255) / 256, 256, 0, stream>>>(edst, E, deg);
  scan_partial<<<NB, 256, 0, stream>>>(deg, N, bsum);
  scan_bsums<<<1, 256, 0, stream>>>(bsum, NB);
  scan_final<<<NB, 256, 0, stream>>>(deg, N, bsum, offs, cursor);
  scatter_csr<<<(E + N + 255) / 256, 256, 0, stream>>>(esrc, edst, E, N,
                                                       cursor, csr);

  for (int layer = 0; layer < 2; ++layer) {
    const float* Xf = layer ? h1 : h0;
    const unsigned* Xb = layer ? h1b : h0b;
    const unsigned char* X8 = layer ? h1f8 : h0f8;
    float* Yf = layer ? h0 : h1;
    unsigned* Yb = layer ? h0b : h1b;          // written only for layer 0
    unsigned char* Y8 = layer ? h0f8 : h1f8;   // written only for layer 0
    edge_stats_f8<<<2048, 256, 0, stream>>>(X8, csr, offs, N, stat);
    node_scores_att<<<1024, 256, 0, stream>>>(
        Xf, stat, gsw[layer], gsb[layer], gdw[layer], gdb[layer], gtq[layer],
        a_src, a_dst, N, (float)E);
    aggregate_bf<<<2048, 256, 0, stream>>>(
        Xb, csr, offs, a_src, a_dst, gbias[layer], Yf, Yb, Y8, N,
        layer == 0 ? 1 : 0, layer == 0 ? 1 : 0, stat);
  }

  // GEMM2: out = h0 @ W2^T + b2   (h0 holds conv2 output, fp32)
  gemm_bias<64, false><<<(N + 127) / 128, 256, 0, stream>>>(
      h0, W2, b2, (float*)d_out, nullptr, nullptr, N);
}